// Round 9
// baseline (396.974 us; speedup 1.0000x reference)
//
#include <hip/hip_runtime.h>

#define RMAX 60
#define KTAPS 121          // 2*RMAX+1
#define WP 144             // weight row, tap o at index 67+o, zeros outside
#define NC 3
#define NH 256
#define NW 256
#define NPLANE (64 * NC)   // 192
#define HPB 16             // hpass blocks per plane (x4 waves = 64 4-row tiles)
#define VPB 8              // vpass blocks per plane (x4 waves = 32 8-row tiles)

__device__ __forceinline__ int refl(int q) {
    // jnp.pad mode='reflect'; valid for q in (-NH, 2*NH-1). Branch-free.
    q = q < 0 ? -q : q;
    int d = (NH - 1) - q;
    d = d < 0 ? -d : d;
    return (NH - 1) - d;
}

// One block (1 wave) per sample: normalized, zero-padded kernel row (center 67).
__global__ void wgen(const int* __restrict__ steps, const float* __restrict__ sigmas,
                     float* __restrict__ wpad) {
    const int b = blockIdx.x;
    const int t = threadIdx.x;               // 0..63
    const float sg = sigmas[steps[b]];
    const float r = ceilf(3.0f * sg);
    const float inv2s2 = 0.5f / (sg * sg);
    const float o0 = (float)(t - RMAX);
    float w0 = (fabsf(o0) <= r) ? expf(-o0 * o0 * inv2s2) : 0.0f;
    const int t1 = t + 64;
    float w1 = 0.0f;
    if (t1 < KTAPS) {
        const float o1 = (float)(t1 - RMAX);
        w1 = (fabsf(o1) <= r) ? expf(-o1 * o1 * inv2s2) : 0.0f;
    }
    float s = w0 + w1;
#pragma unroll
    for (int off = 32; off > 0; off >>= 1) s += __shfl_down(s, off);
    const float inv = 1.0f / __shfl(s, 0);
    float* row = wpad + b * WP;
    if (t < 7) row[t] = 0.0f;                          // [0,7)
    row[7 + t] = w0 * inv;                             // [7,71)
    row[7 + t1] = (t1 < KTAPS) ? w1 * inv : 0.0f;      // [71,135)
    if (t < 9) row[135 + t] = 0.0f;                    // [135,144)
}

// ---------- horizontal body: fully static per radius-bucket RP ----------
template<int RP>
__device__ __forceinline__ void hbody(const float (* __restrict__ sr)[384],
                                      const float* __restrict__ wl, int x0,
                                      float4 acc[4]) {
#pragma unroll
    for (int m = 0; m < RP / 2 + 1; ++m) {
        const int q0 = 64 - RP + 4 * m;                // compile-time
        const float4 wa = *(const float4*)&wl[q0];
        const float4 wb = *(const float4*)&wl[q0 + 4];
#pragma unroll
        for (int rr = 0; rr < 4; ++rr) {
            const float4 v = *(const float4*)&sr[rr][q0 - 4 + x0];
            acc[rr].x = fmaf(v.x, wa.w, acc[rr].x);
            acc[rr].x = fmaf(v.y, wb.x, acc[rr].x);
            acc[rr].x = fmaf(v.z, wb.y, acc[rr].x);
            acc[rr].x = fmaf(v.w, wb.z, acc[rr].x);
            acc[rr].y = fmaf(v.x, wa.z, acc[rr].y);
            acc[rr].y = fmaf(v.y, wa.w, acc[rr].y);
            acc[rr].y = fmaf(v.z, wb.x, acc[rr].y);
            acc[rr].y = fmaf(v.w, wb.y, acc[rr].y);
            acc[rr].z = fmaf(v.x, wa.y, acc[rr].z);
            acc[rr].z = fmaf(v.y, wa.z, acc[rr].z);
            acc[rr].z = fmaf(v.z, wa.w, acc[rr].z);
            acc[rr].z = fmaf(v.w, wb.x, acc[rr].z);
            acc[rr].w = fmaf(v.x, wa.x, acc[rr].w);
            acc[rr].w = fmaf(v.y, wa.y, acc[rr].w);
            acc[rr].w = fmaf(v.z, wa.z, acc[rr].w);
            acc[rr].w = fmaf(v.w, wa.w, acc[rr].w);
        }
    }
}

// Horizontal pass: one 4-row tile per wave, LDS row staging, flat grid +
// chunked XCD swizzle, 4-bucket static dispatch.
__global__ void hpass(const float* __restrict__ in,
                      const float* __restrict__ wpad,
                      const int* __restrict__ steps,
                      const float* __restrict__ sigmas,
                      float* __restrict__ tmp) {
    __shared__ __align__(16) float wl[WP];
    __shared__ __align__(16) float srow[4][4][384];    // [wave][row][x]
    const int nwg = NPLANE * HPB;                      // 3072
    const int pb = blockIdx.x;
    const int lbid = (pb & 7) * (nwg >> 3) + (pb >> 3);
    const int plane = lbid >> 4;
    const int b = plane / NC;
    const int t = threadIdx.x;
    const int wave = t >> 6, lane = t & 63;
    if (t < WP / 4) ((float4*)wl)[t] = ((const float4*)(wpad + b * WP))[t];

    const int tile = (lbid & 15) * 4 + wave;           // 0..63
    const int ybase = tile * 4;
    const float* __restrict__ plptr = in + ((size_t)plane << 16);
    float (* __restrict__ sr)[384] = srow[wave];
    const int x0 = lane * 4;

    // stage 4 reflect-padded rows
#pragma unroll
    for (int rr = 0; rr < 4; ++rr) {
        const float* __restrict__ row = plptr + ((size_t)(ybase + rr) << 8);
        *(float4*)&sr[rr][60 + x0] = *(const float4*)(row + x0);
        if (lane < 60) {
            sr[rr][lane]       = row[60 - lane];    // left reflect halo
            sr[rr][316 + lane] = row[254 - lane];   // right reflect halo
        }
    }
    __syncthreads();                                   // wl + staged rows ready

    const float sg = sigmas[steps[b]];
    const int rp = ((int)ceilf(3.0f * sg) + 3) & ~3;
    float4 acc[4];
#pragma unroll
    for (int rr = 0; rr < 4; ++rr) acc[rr] = make_float4(0.f, 0.f, 0.f, 0.f);

    if (rp <= 16)      hbody<16>(sr, wl, x0, acc);
    else if (rp <= 32) hbody<32>(sr, wl, x0, acc);
    else if (rp <= 44) hbody<44>(sr, wl, x0, acc);
    else               hbody<60>(sr, wl, x0, acc);

    float* __restrict__ outp = tmp + ((size_t)plane << 16);
#pragma unroll
    for (int rr = 0; rr < 4; ++rr)
        *(float4*)(outp + ((size_t)(ybase + rr) << 8) + x0) = acc[rr];
}

// ---------- vertical body: fully static per radius-bucket RP ----------
template<int RP>
__device__ __forceinline__ void vbody(const float* __restrict__ plptr,
                                      const float* __restrict__ wl,
                                      int yt, int x0, float4 acc[8]) {
#pragma unroll
    for (int it = 0; it < RP / 4 + 1; ++it) {          // 8-row chunks
        const int i0 = yt - RP + 8 * it;
        const int s0 = 60 - RP + 8 * it;               // compile-time
        float wv[16];
#pragma unroll
        for (int k = 0; k < 4; ++k)
            *(float4*)&wv[4 * k] = *(const float4*)&wl[s0 + 4 * k];
        float4 v[8];
        if (i0 >= 0 && i0 + 7 < NH) {                  // wave-uniform fast path
#pragma unroll
            for (int di = 0; di < 8; ++di)
                v[di] = *(const float4*)(plptr + ((size_t)(i0 + di) << 8) + x0);
        } else {
#pragma unroll
            for (int di = 0; di < 8; ++di)
                v[di] = *(const float4*)(plptr + ((size_t)refl(i0 + di) << 8) + x0);
        }
#pragma unroll
        for (int di = 0; di < 8; ++di) {
#pragma unroll
            for (int j = 0; j < 8; ++j) {
                const float w = wv[7 + di - j];        // tap (i0+di)-(yt+j)
                acc[j].x = fmaf(v[di].x, w, acc[j].x);
                acc[j].y = fmaf(v[di].y, w, acc[j].y);
                acc[j].z = fmaf(v[di].z, w, acc[j].z);
                acc[j].w = fmaf(v[di].w, w, acc[j].w);
            }
        }
    }
}

// Vertical pass: one 8-row tile per wave, flat grid + same chunked XCD
// swizzle as hpass (tmp L2 locality), 4-bucket static dispatch.
__global__ void vpass(const float* __restrict__ tmp,
                      const float* __restrict__ wpad,
                      const int* __restrict__ steps,
                      const float* __restrict__ sigmas,
                      float* __restrict__ out) {
    __shared__ __align__(16) float wl[WP];
    const int nwg = NPLANE * VPB;                      // 1536
    const int pb = blockIdx.x;
    const int lbid = (pb & 7) * (nwg >> 3) + (pb >> 3);
    const int plane = lbid >> 3;
    const int b = plane / NC;
    const int t = threadIdx.x;
    if (t < WP / 4) ((float4*)wl)[t] = ((const float4*)(wpad + b * WP))[t];
    __syncthreads();

    const float sg = sigmas[steps[b]];
    const int rp = ((int)ceilf(3.0f * sg) + 3) & ~3;
    const int wave = t >> 6, lane = t & 63;
    const int tile = (lbid & 7) * 4 + wave;            // 0..31
    const int yt = tile * 8;
    const int x0 = lane * 4;
    const float* __restrict__ plptr = tmp + ((size_t)plane << 16);

    float4 acc[8];
#pragma unroll
    for (int j = 0; j < 8; ++j) acc[j] = make_float4(0.f, 0.f, 0.f, 0.f);

    if (rp <= 16)      vbody<16>(plptr, wl, yt, x0, acc);
    else if (rp <= 32) vbody<32>(plptr, wl, yt, x0, acc);
    else if (rp <= 44) vbody<44>(plptr, wl, yt, x0, acc);
    else               vbody<60>(plptr, wl, yt, x0, acc);

    float* __restrict__ outp = out + ((size_t)plane << 16) + x0;
#pragma unroll
    for (int j = 0; j < 8; ++j)
        *(float4*)(outp + ((size_t)(yt + j) << 8)) = acc[j];
}

extern "C" void kernel_launch(void* const* d_in, const int* in_sizes, int n_in,
                              void* d_out, int out_size, void* d_ws, size_t ws_size,
                              hipStream_t stream) {
    const float* x      = (const float*)d_in[0];
    const int*   steps  = (const int*)d_in[1];
    const float* sigmas = (const float*)d_in[2];
    float* out = (float*)d_out;
    const int B = in_sizes[1];              // 64

    float* wpad = (float*)d_ws;                                   // B*WP floats
    float* tmp  = wpad + (size_t)B * WP;                          // B*C*H*W floats

    wgen<<<dim3(B), dim3(64), 0, stream>>>(steps, sigmas, wpad);
    hpass<<<dim3(NPLANE * HPB), dim3(256), 0, stream>>>(x, wpad, steps, sigmas, tmp);
    vpass<<<dim3(NPLANE * VPB), dim3(256), 0, stream>>>(tmp, wpad, steps, sigmas, out);
}

// Round 10
// 81.953 us; speedup vs baseline: 4.8439x; 4.8439x over previous
//
#include <hip/hip_runtime.h>

#define RMAX 60
#define KTAPS 121          // 2*RMAX+1
#define WP 144             // weight row, tap o at index 67+o, zeros outside
#define NC 3
#define NH 256
#define NW 256
#define NPLANE (64 * NC)   // 192
#define HPB 16             // hpass blocks per plane (x4 waves = 64 4-row tiles)
#define VPB 8              // vpass blocks per plane (x4 waves = 32 8-row tiles)

__device__ __forceinline__ int refl(int q) {
    // jnp.pad mode='reflect'; valid for q in (-NH, 2*NH-1). Branch-free.
    q = q < 0 ? -q : q;
    int d = (NH - 1) - q;
    d = d < 0 ? -d : d;
    return (NH - 1) - d;
}

// One block (1 wave) per sample: normalized, zero-padded kernel row (center 67).
__global__ void wgen(const int* __restrict__ steps, const float* __restrict__ sigmas,
                     float* __restrict__ wpad) {
    const int b = blockIdx.x;
    const int t = threadIdx.x;               // 0..63
    const float sg = sigmas[steps[b]];
    const float r = ceilf(3.0f * sg);
    const float inv2s2 = 0.5f / (sg * sg);
    const float o0 = (float)(t - RMAX);
    float w0 = (fabsf(o0) <= r) ? expf(-o0 * o0 * inv2s2) : 0.0f;
    const int t1 = t + 64;
    float w1 = 0.0f;
    if (t1 < KTAPS) {
        const float o1 = (float)(t1 - RMAX);
        w1 = (fabsf(o1) <= r) ? expf(-o1 * o1 * inv2s2) : 0.0f;
    }
    float s = w0 + w1;
#pragma unroll
    for (int off = 32; off > 0; off >>= 1) s += __shfl_down(s, off);
    const float inv = 1.0f / __shfl(s, 0);
    float* row = wpad + b * WP;
    if (t < 7) row[t] = 0.0f;                          // [0,7)
    row[7 + t] = w0 * inv;                             // [7,71)
    row[7 + t1] = (t1 < KTAPS) ? w1 * inv : 0.0f;      // [71,135)
    if (t < 9) row[135 + t] = 0.0f;                    // [135,144)
}

// ---------- horizontal body: fully static per radius-bucket RP ----------
template<int RP>
__device__ __forceinline__ void hbody(const float (* __restrict__ sr)[384],
                                      const float* __restrict__ wl, int x0,
                                      float4 acc[4]) {
#pragma unroll
    for (int m = 0; m < RP / 2 + 1; ++m) {
        const int q0 = 64 - RP + 4 * m;                // compile-time
        const float4 wa = *(const float4*)&wl[q0];
        const float4 wb = *(const float4*)&wl[q0 + 4];
#pragma unroll
        for (int rr = 0; rr < 4; ++rr) {
            const float4 v = *(const float4*)&sr[rr][q0 - 4 + x0];
            acc[rr].x = fmaf(v.x, wa.w, acc[rr].x);
            acc[rr].x = fmaf(v.y, wb.x, acc[rr].x);
            acc[rr].x = fmaf(v.z, wb.y, acc[rr].x);
            acc[rr].x = fmaf(v.w, wb.z, acc[rr].x);
            acc[rr].y = fmaf(v.x, wa.z, acc[rr].y);
            acc[rr].y = fmaf(v.y, wa.w, acc[rr].y);
            acc[rr].y = fmaf(v.z, wb.x, acc[rr].y);
            acc[rr].y = fmaf(v.w, wb.y, acc[rr].y);
            acc[rr].z = fmaf(v.x, wa.y, acc[rr].z);
            acc[rr].z = fmaf(v.y, wa.z, acc[rr].z);
            acc[rr].z = fmaf(v.z, wa.w, acc[rr].z);
            acc[rr].z = fmaf(v.w, wb.x, acc[rr].z);
            acc[rr].w = fmaf(v.x, wa.x, acc[rr].w);
            acc[rr].w = fmaf(v.y, wa.y, acc[rr].w);
            acc[rr].w = fmaf(v.z, wa.z, acc[rr].w);
            acc[rr].w = fmaf(v.w, wa.w, acc[rr].w);
        }
    }
}

// Horizontal pass: one 4-row tile per wave, LDS row staging, flat grid +
// chunked XCD swizzle, 4-bucket static dispatch. (unchanged from R9 — fast)
__global__ void hpass(const float* __restrict__ in,
                      const float* __restrict__ wpad,
                      const int* __restrict__ steps,
                      const float* __restrict__ sigmas,
                      float* __restrict__ tmp) {
    __shared__ __align__(16) float wl[WP];
    __shared__ __align__(16) float srow[4][4][384];    // [wave][row][x]
    const int nwg = NPLANE * HPB;                      // 3072
    const int pb = blockIdx.x;
    const int lbid = (pb & 7) * (nwg >> 3) + (pb >> 3);
    const int plane = lbid >> 4;
    const int b = plane / NC;
    const int t = threadIdx.x;
    const int wave = t >> 6, lane = t & 63;
    if (t < WP / 4) ((float4*)wl)[t] = ((const float4*)(wpad + b * WP))[t];

    const int tile = (lbid & 15) * 4 + wave;           // 0..63
    const int ybase = tile * 4;
    const float* __restrict__ plptr = in + ((size_t)plane << 16);
    float (* __restrict__ sr)[384] = srow[wave];
    const int x0 = lane * 4;

    // stage 4 reflect-padded rows
#pragma unroll
    for (int rr = 0; rr < 4; ++rr) {
        const float* __restrict__ row = plptr + ((size_t)(ybase + rr) << 8);
        *(float4*)&sr[rr][60 + x0] = *(const float4*)(row + x0);
        if (lane < 60) {
            sr[rr][lane]       = row[60 - lane];    // left reflect halo
            sr[rr][316 + lane] = row[254 - lane];   // right reflect halo
        }
    }
    __syncthreads();                                   // wl + staged rows ready

    const float sg = sigmas[steps[b]];
    const int rp = ((int)ceilf(3.0f * sg) + 3) & ~3;
    float4 acc[4];
#pragma unroll
    for (int rr = 0; rr < 4; ++rr) acc[rr] = make_float4(0.f, 0.f, 0.f, 0.f);

    if (rp <= 16)      hbody<16>(sr, wl, x0, acc);
    else if (rp <= 32) hbody<32>(sr, wl, x0, acc);
    else if (rp <= 44) hbody<44>(sr, wl, x0, acc);
    else               hbody<60>(sr, wl, x0, acc);

    float* __restrict__ outp = tmp + ((size_t)plane << 16);
#pragma unroll
    for (int rr = 0; rr < 4; ++rr)
        *(float4*)(outp + ((size_t)(ybase + rr) << 8) + x0) = acc[rr];
}

// ---------- vertical body: R2-proven form — loads consumed immediately,
// no input array, no boundary branch (refl always). ----------
template<int RP>
__device__ __forceinline__ void vbody(const float* __restrict__ plptr,
                                      const float* __restrict__ wl,
                                      int yt, int x0, float4 acc[8]) {
#pragma unroll
    for (int it = 0; it < RP / 4 + 1; ++it) {          // 8-row chunks
        const int i0 = yt - RP + 8 * it;
        const int s0 = 60 - RP + 8 * it;               // compile-time
        float wv[16];
#pragma unroll
        for (int k = 0; k < 4; ++k)
            *(float4*)&wv[4 * k] = *(const float4*)&wl[s0 + 4 * k];
#pragma unroll
        for (int di = 0; di < 8; ++di) {
            const int ir = refl(i0 + di);
            const float4 v = *(const float4*)(plptr + ((size_t)ir << 8) + x0);
#pragma unroll
            for (int j = 0; j < 8; ++j) {
                const float w = wv[7 + di - j];        // tap (i0+di)-(yt+j)
                acc[j].x = fmaf(v.x, w, acc[j].x);
                acc[j].y = fmaf(v.y, w, acc[j].y);
                acc[j].z = fmaf(v.z, w, acc[j].z);
                acc[j].w = fmaf(v.w, w, acc[j].w);
            }
        }
    }
}

// Vertical pass: one 8-row tile per wave, flat grid + same chunked XCD
// swizzle as hpass (tmp L2 locality), 4-bucket static dispatch.
__global__ void vpass(const float* __restrict__ tmp,
                      const float* __restrict__ wpad,
                      const int* __restrict__ steps,
                      const float* __restrict__ sigmas,
                      float* __restrict__ out) {
    __shared__ __align__(16) float wl[WP];
    const int nwg = NPLANE * VPB;                      // 1536
    const int pb = blockIdx.x;
    const int lbid = (pb & 7) * (nwg >> 3) + (pb >> 3);
    const int plane = lbid >> 3;
    const int b = plane / NC;
    const int t = threadIdx.x;
    if (t < WP / 4) ((float4*)wl)[t] = ((const float4*)(wpad + b * WP))[t];
    __syncthreads();

    const float sg = sigmas[steps[b]];
    const int rp = ((int)ceilf(3.0f * sg) + 3) & ~3;
    const int wave = t >> 6, lane = t & 63;
    const int tile = (lbid & 7) * 4 + wave;            // 0..31
    const int yt = tile * 8;
    const int x0 = lane * 4;
    const float* __restrict__ plptr = tmp + ((size_t)plane << 16);

    float4 acc[8];
#pragma unroll
    for (int j = 0; j < 8; ++j) acc[j] = make_float4(0.f, 0.f, 0.f, 0.f);

    if (rp <= 16)      vbody<16>(plptr, wl, yt, x0, acc);
    else if (rp <= 32) vbody<32>(plptr, wl, yt, x0, acc);
    else if (rp <= 44) vbody<44>(plptr, wl, yt, x0, acc);
    else               vbody<60>(plptr, wl, yt, x0, acc);

    float* __restrict__ outp = out + ((size_t)plane << 16) + x0;
#pragma unroll
    for (int j = 0; j < 8; ++j)
        *(float4*)(outp + ((size_t)(yt + j) << 8)) = acc[j];
}

extern "C" void kernel_launch(void* const* d_in, const int* in_sizes, int n_in,
                              void* d_out, int out_size, void* d_ws, size_t ws_size,
                              hipStream_t stream) {
    const float* x      = (const float*)d_in[0];
    const int*   steps  = (const int*)d_in[1];
    const float* sigmas = (const float*)d_in[2];
    float* out = (float*)d_out;
    const int B = in_sizes[1];              // 64

    float* wpad = (float*)d_ws;                                   // B*WP floats
    float* tmp  = wpad + (size_t)B * WP;                          // B*C*H*W floats

    wgen<<<dim3(B), dim3(64), 0, stream>>>(steps, sigmas, wpad);
    hpass<<<dim3(NPLANE * HPB), dim3(256), 0, stream>>>(x, wpad, steps, sigmas, tmp);
    vpass<<<dim3(NPLANE * VPB), dim3(256), 0, stream>>>(tmp, wpad, steps, sigmas, out);
}

// Round 11
// 77.673 us; speedup vs baseline: 5.1108x; 1.0551x over previous
//
#include <hip/hip_runtime.h>

#define RMAX 60
#define KTAPS 121          // 2*RMAX+1
#define WP 144             // weight row, tap o at index 67+o, zeros outside
#define NC 3
#define NH 256
#define NW 256
#define NPLANE (64 * NC)   // 192
#define HPB 16             // hpass blocks per plane (x4 waves = 64 4-row tiles)
#define VBANDS 8           // vpass bands per plane (32 rows per band)

__device__ __forceinline__ int refl(int q) {
    // jnp.pad mode='reflect'; valid for q in (-NH, 2*NH-1). Branch-free.
    q = q < 0 ? -q : q;
    int d = (NH - 1) - q;
    d = d < 0 ? -d : d;
    return (NH - 1) - d;
}

// One block (1 wave) per sample: normalized, zero-padded kernel row (center 67).
__global__ void wgen(const int* __restrict__ steps, const float* __restrict__ sigmas,
                     float* __restrict__ wpad) {
    const int b = blockIdx.x;
    const int t = threadIdx.x;               // 0..63
    const float sg = sigmas[steps[b]];
    const float r = ceilf(3.0f * sg);
    const float inv2s2 = 0.5f / (sg * sg);
    const float o0 = (float)(t - RMAX);
    float w0 = (fabsf(o0) <= r) ? expf(-o0 * o0 * inv2s2) : 0.0f;
    const int t1 = t + 64;
    float w1 = 0.0f;
    if (t1 < KTAPS) {
        const float o1 = (float)(t1 - RMAX);
        w1 = (fabsf(o1) <= r) ? expf(-o1 * o1 * inv2s2) : 0.0f;
    }
    float s = w0 + w1;
#pragma unroll
    for (int off = 32; off > 0; off >>= 1) s += __shfl_down(s, off);
    const float inv = 1.0f / __shfl(s, 0);
    float* row = wpad + b * WP;
    if (t < 7) row[t] = 0.0f;                          // [0,7)
    row[7 + t] = w0 * inv;                             // [7,71)
    row[7 + t1] = (t1 < KTAPS) ? w1 * inv : 0.0f;      // [71,135)
    if (t < 9) row[135 + t] = 0.0f;                    // [135,144)
}

// ---------- horizontal body: fully static per radius-bucket RP ----------
template<int RP>
__device__ __forceinline__ void hbody(const float (* __restrict__ sr)[384],
                                      const float* __restrict__ wl, int x0,
                                      float4 acc[4]) {
#pragma unroll
    for (int m = 0; m < RP / 2 + 1; ++m) {
        const int q0 = 64 - RP + 4 * m;                // compile-time
        const float4 wa = *(const float4*)&wl[q0];
        const float4 wb = *(const float4*)&wl[q0 + 4];
#pragma unroll
        for (int rr = 0; rr < 4; ++rr) {
            const float4 v = *(const float4*)&sr[rr][q0 - 4 + x0];
            acc[rr].x = fmaf(v.x, wa.w, acc[rr].x);
            acc[rr].x = fmaf(v.y, wb.x, acc[rr].x);
            acc[rr].x = fmaf(v.z, wb.y, acc[rr].x);
            acc[rr].x = fmaf(v.w, wb.z, acc[rr].x);
            acc[rr].y = fmaf(v.x, wa.z, acc[rr].y);
            acc[rr].y = fmaf(v.y, wa.w, acc[rr].y);
            acc[rr].y = fmaf(v.z, wb.x, acc[rr].y);
            acc[rr].y = fmaf(v.w, wb.y, acc[rr].y);
            acc[rr].z = fmaf(v.x, wa.y, acc[rr].z);
            acc[rr].z = fmaf(v.y, wa.z, acc[rr].z);
            acc[rr].z = fmaf(v.z, wa.w, acc[rr].z);
            acc[rr].z = fmaf(v.w, wb.x, acc[rr].z);
            acc[rr].w = fmaf(v.x, wa.x, acc[rr].w);
            acc[rr].w = fmaf(v.y, wa.y, acc[rr].w);
            acc[rr].w = fmaf(v.z, wa.z, acc[rr].w);
            acc[rr].w = fmaf(v.w, wa.w, acc[rr].w);
        }
    }
}

// Horizontal pass: one 4-row tile per wave, LDS row staging, flat grid +
// chunked XCD swizzle, 4-bucket static dispatch. (unchanged from R10 — fast)
__global__ void hpass(const float* __restrict__ in,
                      const float* __restrict__ wpad,
                      const int* __restrict__ steps,
                      const float* __restrict__ sigmas,
                      float* __restrict__ tmp) {
    __shared__ __align__(16) float wl[WP];
    __shared__ __align__(16) float srow[4][4][384];    // [wave][row][x]
    const int nwg = NPLANE * HPB;                      // 3072
    const int pb = blockIdx.x;
    const int lbid = (pb & 7) * (nwg >> 3) + (pb >> 3);
    const int plane = lbid >> 4;
    const int b = plane / NC;
    const int t = threadIdx.x;
    const int wave = t >> 6, lane = t & 63;
    if (t < WP / 4) ((float4*)wl)[t] = ((const float4*)(wpad + b * WP))[t];

    const int tile = (lbid & 15) * 4 + wave;           // 0..63
    const int ybase = tile * 4;
    const float* __restrict__ plptr = in + ((size_t)plane << 16);
    float (* __restrict__ sr)[384] = srow[wave];
    const int x0 = lane * 4;

    // stage 4 reflect-padded rows
#pragma unroll
    for (int rr = 0; rr < 4; ++rr) {
        const float* __restrict__ row = plptr + ((size_t)(ybase + rr) << 8);
        *(float4*)&sr[rr][60 + x0] = *(const float4*)(row + x0);
        if (lane < 60) {
            sr[rr][lane]       = row[60 - lane];    // left reflect halo
            sr[rr][316 + lane] = row[254 - lane];   // right reflect halo
        }
    }
    __syncthreads();                                   // wl + staged rows ready

    const float sg = sigmas[steps[b]];
    const int rp = ((int)ceilf(3.0f * sg) + 3) & ~3;
    float4 acc[4];
#pragma unroll
    for (int rr = 0; rr < 4; ++rr) acc[rr] = make_float4(0.f, 0.f, 0.f, 0.f);

    if (rp <= 16)      hbody<16>(sr, wl, x0, acc);
    else if (rp <= 32) hbody<32>(sr, wl, x0, acc);
    else if (rp <= 44) hbody<44>(sr, wl, x0, acc);
    else               hbody<60>(sr, wl, x0, acc);

    float* __restrict__ outp = tmp + ((size_t)plane << 16);
#pragma unroll
    for (int rr = 0; rr < 4; ++rr)
        *(float4*)(outp + ((size_t)(ybase + rr) << 8) + x0) = acc[rr];
}

// Vertical pass: block = 32 output rows (4 waves x 8). Input rows streamed
// through double-buffered LDS in 8-row chunks, staged once per block
// (each wave reg-stages 2 rows), one barrier per chunk. Wave w consumes
// chunk c iff 0 <= c-w <= rp/4 (wave-uniform guard). Global re-reads drop
// from (8+2rp)/8 per wave to (32+2rp)/32 per block. Runtime chunk loop,
// static 256-FMA body, runtime weight offsets (register-safe).
__global__ __launch_bounds__(256, 4) void vpass(const float* __restrict__ tmp,
                                                const float* __restrict__ wpad,
                                                const int* __restrict__ steps,
                                                const float* __restrict__ sigmas,
                                                float* __restrict__ out) {
    __shared__ __align__(16) float wl[WP];
    __shared__ __align__(16) float sb[2][8][256];      // 16 KB dbuf
    const int lbid = blockIdx.x;
    const int plane = lbid % NPLANE;                   // interleave: sigma balance
    const int band  = lbid / NPLANE;                   // 0..7
    const int b = plane / NC;
    const int t = threadIdx.x;
    const int wave = t >> 6, lane = t & 63;
    const int x0 = lane * 4;
    if (t < WP / 4) ((float4*)wl)[t] = ((const float4*)(wpad + b * WP))[t];

    const float sg = sigmas[steps[b]];
    const int rp = ((int)ceilf(3.0f * sg) + 3) & ~3;
    const int y0 = band * 32;
    const int yt = y0 + wave * 8;
    const int nch = (rp >> 2) + 4;                     // 8-row chunks
    const int cmax = rp >> 2;
    const float* __restrict__ plptr = tmp + ((size_t)plane << 16);
    const int d0 = wave * 2;                           // this wave stages rows d0,d0+1

    float4 acc[8];
#pragma unroll
    for (int j = 0; j < 8; ++j) acc[j] = make_float4(0.f, 0.f, 0.f, 0.f);

    // stage chunk 0
    {
        const int i0 = y0 - rp;
        const int ir0 = refl(i0 + d0), ir1 = refl(i0 + d0 + 1);
        *(float4*)&sb[0][d0][x0]     = *(const float4*)(plptr + ((size_t)ir0 << 8) + x0);
        *(float4*)&sb[0][d0 + 1][x0] = *(const float4*)(plptr + ((size_t)ir1 << 8) + x0);
    }
    __syncthreads();                                   // sb[0] + wl ready

    for (int c = 0; c < nch; ++c) {
        const int cur = c & 1, nxt = cur ^ 1;
        if (c + 1 < nch) {                             // prefetch next chunk
            const int i0n = y0 - rp + 8 * (c + 1);
            const int ir0 = refl(i0n + d0), ir1 = refl(i0n + d0 + 1);
            *(float4*)&sb[nxt][d0][x0]     = *(const float4*)(plptr + ((size_t)ir0 << 8) + x0);
            *(float4*)&sb[nxt][d0 + 1][x0] = *(const float4*)(plptr + ((size_t)ir1 << 8) + x0);
        }
        const int u = c - wave;
        if (u >= 0 && u <= cmax) {                     // wave-uniform
            const int s0 = 60 - rp + 8 * u;            // runtime, 16B-aligned
            float wv[16];
#pragma unroll
            for (int k = 0; k < 4; ++k)
                *(float4*)&wv[4 * k] = *(const float4*)&wl[s0 + 4 * k];
#pragma unroll
            for (int di = 0; di < 8; ++di) {
                const float4 v = *(const float4*)&sb[cur][di][x0];
#pragma unroll
                for (int j = 0; j < 8; ++j) {
                    const float w = wv[7 + di - j];    // tap (i0+di)-(yt+j)
                    acc[j].x = fmaf(v.x, w, acc[j].x);
                    acc[j].y = fmaf(v.y, w, acc[j].y);
                    acc[j].z = fmaf(v.z, w, acc[j].z);
                    acc[j].w = fmaf(v.w, w, acc[j].w);
                }
            }
        }
        __syncthreads();
    }

    float* __restrict__ outp = out + ((size_t)plane << 16) + x0;
#pragma unroll
    for (int j = 0; j < 8; ++j)
        *(float4*)(outp + ((size_t)(yt + j) << 8)) = acc[j];
}

extern "C" void kernel_launch(void* const* d_in, const int* in_sizes, int n_in,
                              void* d_out, int out_size, void* d_ws, size_t ws_size,
                              hipStream_t stream) {
    const float* x      = (const float*)d_in[0];
    const int*   steps  = (const int*)d_in[1];
    const float* sigmas = (const float*)d_in[2];
    float* out = (float*)d_out;
    const int B = in_sizes[1];              // 64

    float* wpad = (float*)d_ws;                                   // B*WP floats
    float* tmp  = wpad + (size_t)B * WP;                          // B*C*H*W floats

    wgen<<<dim3(B), dim3(64), 0, stream>>>(steps, sigmas, wpad);
    hpass<<<dim3(NPLANE * HPB), dim3(256), 0, stream>>>(x, wpad, steps, sigmas, tmp);
    vpass<<<dim3(NPLANE * VBANDS), dim3(256), 0, stream>>>(tmp, wpad, steps, sigmas, out);
}

// Round 12
// 75.492 us; speedup vs baseline: 5.2585x; 1.0289x over previous
//
#include <hip/hip_runtime.h>

#define RMAX 60
#define KTAPS 121          // 2*RMAX+1
#define WP 144             // weight row, tap o at index 67+o, zeros outside
#define NC 3
#define NH 256
#define NW 256
#define NPLANE (64 * NC)   // 192
#define HPB 16             // hpass blocks per plane (x4 waves = 64 4-row tiles)
#define VBANDS 8           // vpass bands per plane (32 rows per band)

__device__ __forceinline__ int refl(int q) {
    // jnp.pad mode='reflect'; valid for q in (-NH, 2*NH-1). Branch-free.
    q = q < 0 ? -q : q;
    int d = (NH - 1) - q;
    d = d < 0 ? -d : d;
    return (NH - 1) - d;
}

// One block (1 wave) per sample: normalized, zero-padded kernel row (center 67).
__global__ void wgen(const int* __restrict__ steps, const float* __restrict__ sigmas,
                     float* __restrict__ wpad) {
    const int b = blockIdx.x;
    const int t = threadIdx.x;               // 0..63
    const float sg = sigmas[steps[b]];
    const float r = ceilf(3.0f * sg);
    const float inv2s2 = 0.5f / (sg * sg);
    const float o0 = (float)(t - RMAX);
    float w0 = (fabsf(o0) <= r) ? expf(-o0 * o0 * inv2s2) : 0.0f;
    const int t1 = t + 64;
    float w1 = 0.0f;
    if (t1 < KTAPS) {
        const float o1 = (float)(t1 - RMAX);
        w1 = (fabsf(o1) <= r) ? expf(-o1 * o1 * inv2s2) : 0.0f;
    }
    float s = w0 + w1;
#pragma unroll
    for (int off = 32; off > 0; off >>= 1) s += __shfl_down(s, off);
    const float inv = 1.0f / __shfl(s, 0);
    float* row = wpad + b * WP;
    if (t < 7) row[t] = 0.0f;                          // [0,7)
    row[7 + t] = w0 * inv;                             // [7,71)
    row[7 + t1] = (t1 < KTAPS) ? w1 * inv : 0.0f;      // [71,135)
    if (t < 9) row[135 + t] = 0.0f;                    // [135,144)
}

// Horizontal pass: one 4-row tile per wave, LDS row staging, flat grid +
// chunked XCD swizzle. Exact-rp runtime M loop (peel 1 + unroll 2; M odd)
// — R5-proven structure — plus ROLLING WEIGHTS: wa(m+1)==wb(m), so each
// step loads only ONE weight float4 (5 ds_reads per 64 FMAs instead of 6).
__global__ void hpass(const float* __restrict__ in,
                      const float* __restrict__ wpad,
                      const int* __restrict__ steps,
                      const float* __restrict__ sigmas,
                      float* __restrict__ tmp) {
    __shared__ __align__(16) float wl[WP];
    __shared__ __align__(16) float srow[4][4][384];    // [wave][row][x]
    const int nwg = NPLANE * HPB;                      // 3072, %8==0
    const int pb = blockIdx.x;
    const int lbid = (pb & 7) * (nwg >> 3) + (pb >> 3);
    const int plane = lbid >> 4;
    const int b = plane / NC;
    const int t = threadIdx.x;
    const int wave = t >> 6, lane = t & 63;
    if (t < WP / 4) ((float4*)wl)[t] = ((const float4*)(wpad + b * WP))[t];

    const int tile = (lbid & 15) * 4 + wave;           // 0..63
    const int ybase = tile * 4;
    const float* __restrict__ plptr = in + ((size_t)plane << 16);
    float (* __restrict__ sr)[384] = srow[wave];
    const int x0 = lane * 4;

    // stage 4 reflect-padded rows
#pragma unroll
    for (int rr = 0; rr < 4; ++rr) {
        const float* __restrict__ row = plptr + ((size_t)(ybase + rr) << 8);
        *(float4*)&sr[rr][60 + x0] = *(const float4*)(row + x0);
        if (lane < 60) {
            sr[rr][lane]       = row[60 - lane];    // left reflect halo
            sr[rr][316 + lane] = row[254 - lane];   // right reflect halo
        }
    }
    __syncthreads();                                   // wl + staged rows ready

    const float sg = sigmas[steps[b]];
    const int rp = ((int)ceilf(3.0f * sg) + 3) & ~3;
    float4 acc[4];
#pragma unroll
    for (int rr = 0; rr < 4; ++rr) acc[rr] = make_float4(0.f, 0.f, 0.f, 0.f);

    // Rolling-weight HSTEP: uses carried wa and freshly-loaded wb, then
    // advances (wa = wb, q0 += 4).
#define HSTEP_R() do {                                                        \
    const float4 wb = *(const float4*)&wl[q0 + 4];                            \
    _Pragma("unroll")                                                         \
    for (int rr = 0; rr < 4; ++rr) {                                          \
        const float4 v = *(const float4*)&sr[rr][q0 - 4 + x0];                \
        acc[rr].x = fmaf(v.x, wa.w, acc[rr].x);                               \
        acc[rr].x = fmaf(v.y, wb.x, acc[rr].x);                               \
        acc[rr].x = fmaf(v.z, wb.y, acc[rr].x);                               \
        acc[rr].x = fmaf(v.w, wb.z, acc[rr].x);                               \
        acc[rr].y = fmaf(v.x, wa.z, acc[rr].y);                               \
        acc[rr].y = fmaf(v.y, wa.w, acc[rr].y);                               \
        acc[rr].y = fmaf(v.z, wb.x, acc[rr].y);                               \
        acc[rr].y = fmaf(v.w, wb.y, acc[rr].y);                               \
        acc[rr].z = fmaf(v.x, wa.y, acc[rr].z);                               \
        acc[rr].z = fmaf(v.y, wa.z, acc[rr].z);                               \
        acc[rr].z = fmaf(v.z, wa.w, acc[rr].z);                               \
        acc[rr].z = fmaf(v.w, wb.x, acc[rr].z);                               \
        acc[rr].w = fmaf(v.x, wa.x, acc[rr].w);                               \
        acc[rr].w = fmaf(v.y, wa.y, acc[rr].w);                               \
        acc[rr].w = fmaf(v.z, wa.z, acc[rr].w);                               \
        acc[rr].w = fmaf(v.w, wa.w, acc[rr].w);                               \
    }                                                                         \
    wa = wb;                                                                  \
    q0 += 4;                                                                  \
} while (0)

    // q0 walks 64-rp .. 64+rp step 4; M = rp/2+1 steps (odd): peel 1, unroll 2
    const int qend = 64 + rp;
    int q0 = 64 - rp;
    float4 wa = *(const float4*)&wl[q0];
    HSTEP_R();
    while (q0 <= qend) {
        HSTEP_R();
        HSTEP_R();
    }
#undef HSTEP_R

    float* __restrict__ outp = tmp + ((size_t)plane << 16);
#pragma unroll
    for (int rr = 0; rr < 4; ++rr)
        *(float4*)(outp + ((size_t)(ybase + rr) << 8) + x0) = acc[rr];
}

// Vertical pass: block = 32 output rows (4 waves x 8). Input rows streamed
// through double-buffered LDS in 8-row chunks, staged once per block
// (each wave reg-stages 2 rows), one barrier per chunk. Wave w consumes
// chunk c iff 0 <= c-w <= rp/4 (wave-uniform guard). (unchanged from R11)
__global__ __launch_bounds__(256, 4) void vpass(const float* __restrict__ tmp,
                                                const float* __restrict__ wpad,
                                                const int* __restrict__ steps,
                                                const float* __restrict__ sigmas,
                                                float* __restrict__ out) {
    __shared__ __align__(16) float wl[WP];
    __shared__ __align__(16) float sb[2][8][256];      // 16 KB dbuf
    const int lbid = blockIdx.x;
    const int plane = lbid % NPLANE;                   // interleave: sigma balance
    const int band  = lbid / NPLANE;                   // 0..7
    const int b = plane / NC;
    const int t = threadIdx.x;
    const int wave = t >> 6, lane = t & 63;
    const int x0 = lane * 4;
    if (t < WP / 4) ((float4*)wl)[t] = ((const float4*)(wpad + b * WP))[t];

    const float sg = sigmas[steps[b]];
    const int rp = ((int)ceilf(3.0f * sg) + 3) & ~3;
    const int y0 = band * 32;
    const int yt = y0 + wave * 8;
    const int nch = (rp >> 2) + 4;                     // 8-row chunks
    const int cmax = rp >> 2;
    const float* __restrict__ plptr = tmp + ((size_t)plane << 16);
    const int d0 = wave * 2;                           // this wave stages rows d0,d0+1

    float4 acc[8];
#pragma unroll
    for (int j = 0; j < 8; ++j) acc[j] = make_float4(0.f, 0.f, 0.f, 0.f);

    // stage chunk 0
    {
        const int i0 = y0 - rp;
        const int ir0 = refl(i0 + d0), ir1 = refl(i0 + d0 + 1);
        *(float4*)&sb[0][d0][x0]     = *(const float4*)(plptr + ((size_t)ir0 << 8) + x0);
        *(float4*)&sb[0][d0 + 1][x0] = *(const float4*)(plptr + ((size_t)ir1 << 8) + x0);
    }
    __syncthreads();                                   // sb[0] + wl ready

    for (int c = 0; c < nch; ++c) {
        const int cur = c & 1, nxt = cur ^ 1;
        if (c + 1 < nch) {                             // prefetch next chunk
            const int i0n = y0 - rp + 8 * (c + 1);
            const int ir0 = refl(i0n + d0), ir1 = refl(i0n + d0 + 1);
            *(float4*)&sb[nxt][d0][x0]     = *(const float4*)(plptr + ((size_t)ir0 << 8) + x0);
            *(float4*)&sb[nxt][d0 + 1][x0] = *(const float4*)(plptr + ((size_t)ir1 << 8) + x0);
        }
        const int u = c - wave;
        if (u >= 0 && u <= cmax) {                     // wave-uniform
            const int s0 = 60 - rp + 8 * u;            // runtime, 16B-aligned
            float wv[16];
#pragma unroll
            for (int k = 0; k < 4; ++k)
                *(float4*)&wv[4 * k] = *(const float4*)&wl[s0 + 4 * k];
#pragma unroll
            for (int di = 0; di < 8; ++di) {
                const float4 v = *(const float4*)&sb[cur][di][x0];
#pragma unroll
                for (int j = 0; j < 8; ++j) {
                    const float w = wv[7 + di - j];    // tap (i0+di)-(yt+j)
                    acc[j].x = fmaf(v.x, w, acc[j].x);
                    acc[j].y = fmaf(v.y, w, acc[j].y);
                    acc[j].z = fmaf(v.z, w, acc[j].z);
                    acc[j].w = fmaf(v.w, w, acc[j].w);
                }
            }
        }
        __syncthreads();
    }

    float* __restrict__ outp = out + ((size_t)plane << 16) + x0;
#pragma unroll
    for (int j = 0; j < 8; ++j)
        *(float4*)(outp + ((size_t)(yt + j) << 8)) = acc[j];
}

extern "C" void kernel_launch(void* const* d_in, const int* in_sizes, int n_in,
                              void* d_out, int out_size, void* d_ws, size_t ws_size,
                              hipStream_t stream) {
    const float* x      = (const float*)d_in[0];
    const int*   steps  = (const int*)d_in[1];
    const float* sigmas = (const float*)d_in[2];
    float* out = (float*)d_out;
    const int B = in_sizes[1];              // 64

    float* wpad = (float*)d_ws;                                   // B*WP floats
    float* tmp  = wpad + (size_t)B * WP;                          // B*C*H*W floats

    wgen<<<dim3(B), dim3(64), 0, stream>>>(steps, sigmas, wpad);
    hpass<<<dim3(NPLANE * HPB), dim3(256), 0, stream>>>(x, wpad, steps, sigmas, tmp);
    vpass<<<dim3(NPLANE * VBANDS), dim3(256), 0, stream>>>(tmp, wpad, steps, sigmas, out);
}